// Round 1
// baseline (255.761 us; speedup 1.0000x reference)
//
#include <hip/hip_runtime.h>

#define N_NEUR 512
#define B_SZ   16
#define T_STEPS 32
#define NIN    32
#define NOUT   16
#define CAPC   84   // chem nnz/row cap (mean 48.6, sd 6.63)
#define CAPG   52   // gj nnz/row cap   (mean 25.6, sd 4.93)
#define MC     42   // per-thread chem entries (h splits CSR evens/odds)
#define MG     26
#define MCP    21   // packed col words per thread
#define MGP    13
#define LOG2E  1.4426950408889634f

__device__ __forceinline__ float rcp_fast(float x) {
#if __has_builtin(__builtin_amdgcn_rcpf)
    return __builtin_amdgcn_rcpf(x);
#else
    return 1.0f / x;
#endif
}
__device__ __forceinline__ float exp2_fast(float x) {
#if __has_builtin(__builtin_amdgcn_exp2f)
    return __builtin_amdgcn_exp2f(x);
#else
    return exp2f(x);
#endif
}
// cross-pair sum WITHOUT the DS pipe: DPP quad_perm [1,0,3,2]
__device__ __forceinline__ float pair_swap(float x) {
#if __has_builtin(__builtin_amdgcn_mov_dpp)
    return __int_as_float(__builtin_amdgcn_mov_dpp(__float_as_int(x), 0xB1, 0xF, 0xF, true));
#else
    return __shfl_xor(x, 1);
#endif
}

// prep1: per row, softplus + mask + ballot-compact into dense per-row tmp CSR.
__global__ __launch_bounds__(64) void prep1_kernel(
    const float* __restrict__ W,
    const float* __restrict__ mex,
    const float* __restrict__ min_,
    const float* __restrict__ mgj,
    int* __restrict__ key_arr, int* __restrict__ ccA, int* __restrict__ cgA,
    int2* __restrict__ tmpC, int2* __restrict__ tmpG)
{
    const int row  = blockIdx.x;
    const int lane = threadIdx.x;
    const unsigned long long below = (1ull << lane) - 1ull;
    int bc = 0, bg = 0;
    for (int c0 = 0; c0 < N_NEUR; c0 += 64) {
        const int col = c0 + lane;
        const int off = row * N_NEUR + col;
        const float w  = W[off];
        const float sp = fmaxf(w, 0.0f) + log1pf(__expf(-fabsf(w)));  // softplus
        const float dm = mex[off] - min_[off];                         // in {-1,0,1}
        bool a = (dm != 0.0f);
        unsigned long long m = __ballot(a);
        int idx = bc + __popcll(m & below);
        if (a && idx < CAPC)
            tmpC[row * CAPC + idx] = make_int2(col, __float_as_int(sp * dm));
        bc += __popcll(m);

        const float g = mgj[off];
        bool ag = (g != 0.0f);
        m = __ballot(ag);
        idx = bg + __popcll(m & below);
        if (ag && idx < CAPG)
            tmpG[row * CAPG + idx] = make_int2(col, __float_as_int(sp * g));
        bg += __popcll(m);
    }
    if (lane == 0) {
        int cc = min(bc, CAPC), cg = min(bg, CAPG);
        ccA[row] = cc; cgA[row] = cg; key_arr[row] = cc + cg;
    }
}

// rank_kernel: single block, 512 threads. Global sort ranks (asc by nnz),
// order array, and PER-WAVE maxima of cc/cg (needed so prep2's slot layout
// and recur's trip counts agree). rank is written IN PLACE over key_arr
// (safe: keys staged to LDS + barrier before the overwrite).
__global__ __launch_bounds__(512) void rank_kernel(
    int* __restrict__ key_then_rank,          // in: key, out: rank
    const int* __restrict__ ccA, const int* __restrict__ cgA,
    int* __restrict__ order, int* __restrict__ mCwA, int* __restrict__ mGwA)
{
    __shared__ int keyS[N_NEUR];
    __shared__ int mxc[16], mxg[16];
    const int d = threadIdx.x;
    keyS[d] = key_then_rank[d];
    if (d < 16) { mxc[d] = 0; mxg[d] = 0; }
    __syncthreads();
    const int kd = keyS[d];
    int r = 0;
    #pragma unroll 8
    for (int j = 0; j < N_NEUR; ++j) {        // same j across lanes -> LDS broadcast
        int kj = keyS[j];
        r += (kj < kd) || (kj == kd && j < d);
    }
    order[r] = d;
    key_then_rank[d] = r;
    atomicMax(&mxc[r >> 5], ccA[d]);
    atomicMax(&mxg[r >> 5], cgA[d]);
    __syncthreads();
    if (d < 16) {
        mCwA[d] = (mxc[d] + 1) >> 1;          // per-thread slot count (h=0 is the ceil)
        mGwA[d] = (mxg[d] + 1) >> 1;
    }
}

// prep2: per row, split CSR into evens/odds (h); sort each half-list by the
// bank-stagger key ((col&31)-myL)&31; then VALUE-PLACED SLOT SCHEDULING:
// entry with key kappa goes to slot ~ kappa*M/32 on the wave-common grid of
// M = per-wave max trips (from rank_kernel), injectivity repaired by a
// prefix-max scan + cap clamp. At runtime, slot k across all 64 lanes hits
// bank ~ (32k/M + lane)&31 -> aligned 2-way (free) accesses regardless of
// ragged list lengths. Interior empty slots: weight 0, offset 0 (broadcast).
__global__ __launch_bounds__(64) void prep2_kernel(
    const int* __restrict__ rankA, const int* __restrict__ ccA, const int* __restrict__ cgA,
    const int* __restrict__ mCwA, const int* __restrict__ mGwA,
    const int2* __restrict__ tmpC, const int2* __restrict__ tmpG,
    float* __restrict__ wCt, unsigned* __restrict__ cpCt,
    float* __restrict__ wGt, unsigned* __restrict__ cpGt)
{
    __shared__ int   cS[CAPC];  __shared__ float wS[CAPC];
    __shared__ int   cSg[CAPG]; __shared__ float wSg[CAPG];
    __shared__ int   keyS[MC];
    __shared__ int   scol[MC];  __shared__ float sw[MC];
    __shared__ float wOut[MC];  __shared__ int   oOut[MC];
    const int d    = blockIdx.x;
    const int lane = threadIdx.x;
    const int r    = rankA[d];
    const int wv   = r >> 5;
    const int Lb   = 2 * (r & 31);
    const int cc = ccA[d], cg = cgA[d];
    const int Mc = mCwA[wv], Mg = mGwA[wv];

    for (int k = lane; k < CAPC; k += 64) {
        int2 e = (k < cc) ? tmpC[d * CAPC + k] : make_int2(0, 0);
        cS[k] = e.x; wS[k] = __int_as_float(e.y);
    }
    for (int k = lane; k < CAPG; k += 64) {
        int2 e = (k < cg) ? tmpG[d * CAPG + k] : make_int2(0, 0);
        cSg[k] = e.x; wSg[k] = __int_as_float(e.y);
    }
    __syncthreads();

    #pragma unroll
    for (int task = 0; task < 4; ++task) {   // {chem,gj} x {h0,h1}
        const int isG  = task >> 1, h = task & 1;
        const int cnt  = isG ? cg : cc;
        const int m    = (cnt + 1 - h) >> 1;  // entries in this half-list (m <= M)
        const int M    = isG ? Mg : Mc;       // wave-common slot count
        const int Mcap = isG ? MG : MC;
        const int MPc  = isG ? MGP : MCP;
        const int myL  = Lb + h;              // owner lane in the main kernel

        int col = 0; float w = 0.0f; int key = 0;
        if (lane < m) {                       // lane k owns CSR entry 2k+h
            col = isG ? cSg[2 * lane + h] : cS[2 * lane + h];
            w   = isG ? wSg[2 * lane + h] : wS[2 * lane + h];
            key = ((col & 31) - myL) & 31;
            keyS[lane] = key;
        }
        __syncthreads();
        if (lane < m) {                       // stable rank sort by key
            int rk = 0;
            for (int j = 0; j < m; ++j) {
                int kj = keyS[j];
                rk += (kj < key) || (kj == key && j < lane);
            }
            scol[rk] = col; sw[rk] = w;
        }
        if (lane < Mcap) { wOut[lane] = 0.0f; oOut[lane] = 0; }
        __syncthreads();

        // value placement: desired slot d_j = key_j*M/32; repair to strictly
        // increasing via s_j = j + prefmax(d_i - i), clamp to cap M-m+j.
        int a = -(1 << 28);
        int colj = 0; float wj = 0.0f;
        if (lane < m) {
            colj = scol[lane]; wj = sw[lane];
            int kj = ((colj & 31) - myL) & 31;
            a = ((kj * M) >> 5) - lane;
        }
        #pragma unroll
        for (int o = 1; o < 64; o <<= 1) {
            int t2 = __shfl_up(a, o);
            if (lane >= o) a = max(a, t2);
        }
        if (lane < m) {
            int slot = min(lane + a, M - m + lane);
            wOut[slot] = wj;
            oOut[slot] = colj << 2;           // byte offset
        }
        __syncthreads();

        float*    wT = isG ? wGt  : wCt;
        unsigned* cT = isG ? cpGt : cpCt;
        if (lane < Mcap)
            wT[(wv * Mcap + lane) * 64 + myL] = wOut[lane];
        if (lane < MPc) {
            unsigned c0 = (unsigned)oOut[2 * lane];
            unsigned c1 = (unsigned)oOut[2 * lane + 1];
            cT[(wv * MPc + lane) * 64 + myL] = c0 | (c1 << 16);
        }
        __syncthreads();                      // scol/keyS/wOut reused next task
    }
}

#define CHEM_K(k, A) {                                                      \
    unsigned pk = cpC[(k) >> 1];                                            \
    unsigned off = ((k) & 1) ? (pk >> 16) : (pk & 0xffffu);                 \
    A = fmaf(wC[k], *(const float*)((const char*)ObP + off), A); }

#define CHEM_C4(a) { CHEM_K(a, accA) CHEM_K((a)+1, accB) CHEM_K((a)+2, accA) CHEM_K((a)+3, accB) }

#define GJ_K(k, A) {                                                        \
    unsigned pk = cpG[(k) >> 1];                                            \
    unsigned off = ((k) & 1) ? (pk >> 16) : (pk & 0xffffu);                 \
    float Os = *(const float*)((const char*)ObP + off);                     \
    float f = fmaf(20.0f * LOG2E, Os, cE);                                  \
    float tnh = 1.0f - 2.0f * rcp_fast(1.0f + exp2_fast(f));                \
    A = fmaf(wG[k] * Os, tnh, A); }

#define GJ_C4(a) { GJ_K(a, accA) GJ_K((a)+1, accB) GJ_K((a)+2, accA) GJ_K((a)+3, accB) }

// one full time-step; P/Q are COMPILE-TIME buffer indices so the LDS base
// folds into the ds_read immediate offset (no v_add per gather).
#define STEP(t, P, Q) {                                                       \
    float ob_next = (inj && ((t) + 1 < T_STEPS)) ? obs_b[((t) + 1) * NIN + d] : 0.0f; \
    const float* ObP = Ob[P];                                                 \
    const float E_d = Eb[P][d];                                               \
    float accA = 0.0f, accB = 0.0f;                                           \
    CHEM_C4(0)                                                                \
    if ( 4 < mCw) CHEM_C4(4)                                                  \
    if ( 8 < mCw) CHEM_C4(8)                                                  \
    if (12 < mCw) CHEM_C4(12)                                                 \
    if (16 < mCw) CHEM_C4(16)                                                 \
    if (20 < mCw) CHEM_C4(20)                                                 \
    if (24 < mCw) CHEM_C4(24)                                                 \
    if (28 < mCw) CHEM_C4(28)                                                 \
    if (32 < mCw) CHEM_C4(32)                                                 \
    if (36 < mCw) CHEM_C4(36)                                                 \
    if (40 < mCw) { CHEM_K(40, accA) CHEM_K(41, accB) }                       \
    const float cE = -20.0f * LOG2E * E_d;                                    \
    GJ_C4(0)                                                                  \
    if ( 4 < mGw) GJ_C4(4)                                                    \
    if ( 8 < mGw) GJ_C4(8)                                                    \
    if (12 < mGw) GJ_C4(12)                                                   \
    if (16 < mGw) GJ_C4(16)                                                   \
    if (20 < mGw) GJ_C4(20)                                                   \
    if (24 < mGw) { GJ_K(24, accA) GJ_K(25, accB) }                           \
    float acc = accA + accB;                                                  \
    acc += pair_swap(acc);                                                    \
    float curr = fminf(fmaxf(E_d + acc, -10.0f), 10.0f);                      \
    float z = curr - thr_d;                                                   \
    float O_new = (z >= 0.0f) ? z : 0.01f * z;                                \
    float fg = rcp_fast(1.0f + exp2_fast(-10.0f * LOG2E * z));                \
    float dg = rcp_fast(1.0f + exp2_fast(-5.0f * LOG2E * (fabsf(E_d - curr) - 0.01f))); \
    float E_nf  = dg * curr + (1.0f - dg) * (E_d - dec_d);                    \
    float E_new = fg * O_new + (1.0f - fg) * E_nf;                            \
    if (h == 0) {                                                             \
        Eb[Q][d] = inj ? ob_next : E_new;                                     \
        Ob[Q][d] = inj ? ob_next : O_new;                                     \
        if (wr) outp[(t) * NOUT] = E_new;                                     \
    }                                                                         \
    __syncthreads();                                                          \
}

// main: one block per batch, 1024 threads = 2 per neuron (sorted by nnz).
// Lists in registers; fixed-trip unrolled chunks with wave-uniform scalar
// guards (trip counts from rank_kernel so they match the slot layout);
// ONE barrier per step; t-loop unrolled x2 for static LDS bases.
__global__ __launch_bounds__(1024, 1) void recur_kernel(
    const float* __restrict__ obs,
    const float* __restrict__ thr,
    const float* __restrict__ dec,
    const int* __restrict__ order,
    const int* __restrict__ mCwA, const int* __restrict__ mGwA,
    const float* __restrict__ wCt, const unsigned* __restrict__ cpCt,
    const float* __restrict__ wGt, const unsigned* __restrict__ cpGt,
    float* __restrict__ out)
{
    __shared__ float Ob[2][N_NEUR];
    __shared__ float Eb[2][N_NEUR];

    const int b    = blockIdx.x;
    const int tid  = threadIdx.x;
    const int h    = tid & 1;
    const int r    = tid >> 1;            // rank
    const int wv   = tid >> 6;
    const int lane = tid & 63;

    const int d = order[r];
    const float thr_d = thr[d];
    const float dec_d = dec[d];

    const int mCw = __builtin_amdgcn_readfirstlane(mCwA[wv]);
    const int mGw = __builtin_amdgcn_readfirstlane(mGwA[wv]);

    // register-resident lists (zero slots: w=0, offset 0 -> broadcast read)
    float wC[MC]; unsigned cpC[MCP];
    float wG[MG]; unsigned cpG[MGP];
    #pragma unroll
    for (int k = 0; k < MC; ++k)  wC[k]  = wCt[(wv * MC + k) * 64 + lane];
    #pragma unroll
    for (int k = 0; k < MCP; ++k) cpC[k] = cpCt[(wv * MCP + k) * 64 + lane];
    #pragma unroll
    for (int k = 0; k < MG; ++k)  wG[k]  = wGt[(wv * MG + k) * 64 + lane];
    #pragma unroll
    for (int k = 0; k < MGP; ++k) cpG[k] = cpGt[(wv * MGP + k) * 64 + lane];

    const bool inj = (h == 0) && (d < NIN);
    const bool wr  = (h == 0) && (d >= NIN) && (d < NIN + NOUT);
    float* outp = out + (size_t)b * T_STEPS * NOUT + (d - NIN);
    const float* obs_b = obs + b * (T_STEPS * NIN);

    if (h == 0) {
        float v = (d < NIN) ? obs_b[d] : 0.0f;   // state 0 = zeros + obs_0
        Ob[0][d] = v;
        Eb[0][d] = v;
    }
    __syncthreads();

    for (int t = 0; t < T_STEPS; t += 2) {
        STEP(t,     0, 1)
        STEP(t + 1, 1, 0)
    }
}

extern "C" void kernel_launch(void* const* d_in, const int* in_sizes, int n_in,
                              void* d_out, int out_size, void* d_ws, size_t ws_size,
                              hipStream_t stream)
{
    const float* obs  = (const float*)d_in[0];
    const float* W    = (const float*)d_in[1];
    const float* thr  = (const float*)d_in[2];
    const float* dec  = (const float*)d_in[3];
    const float* mex  = (const float*)d_in[4];
    const float* min_ = (const float*)d_in[5];
    const float* mgj  = (const float*)d_in[6];
    float* out = (float*)d_out;

    char* ws = (char*)d_ws;
    int*   key_arr = (int*)(ws);                           // then rank (in place)
    int*   ccA     = (int*)(ws + 2048);
    int*   cgA     = (int*)(ws + 4096);
    int*   order   = (int*)(ws + 6144);
    int2*  tmpC    = (int2*)(ws + 8192);                   // 512*84*8 = 344064
    int2*  tmpG    = (int2*)(ws + 8192 + 344064);          // 512*52*8 = 212992
    float* wCt     = (float*)(ws + 565248);                // 16*42*64*4 = 172032
    unsigned* cpCt = (unsigned*)(ws + 737280);             // 16*21*64*4 =  86016
    float* wGt     = (float*)(ws + 823296);                // 16*26*64*4 = 106496
    unsigned* cpGt = (unsigned*)(ws + 929792);             // 16*13*64*4 =  53248
    int*   mCwA    = (int*)(ws + 983040);                  // 16*4
    int*   mGwA    = (int*)(ws + 983104);                  // 16*4
    // total ws use: ~983.2 KB

    prep1_kernel<<<N_NEUR, 64, 0, stream>>>(W, mex, min_, mgj,
                                            key_arr, ccA, cgA, tmpC, tmpG);
    rank_kernel<<<1, 512, 0, stream>>>(key_arr, ccA, cgA, order, mCwA, mGwA);
    prep2_kernel<<<N_NEUR, 64, 0, stream>>>(key_arr, ccA, cgA, mCwA, mGwA,
                                            tmpC, tmpG, wCt, cpCt, wGt, cpGt);
    recur_kernel<<<B_SZ, 1024, 0, stream>>>(obs, thr, dec,
                                            order, mCwA, mGwA,
                                            wCt, cpCt, wGt, cpGt, out);
}

// Round 2
// 254.878 us; speedup vs baseline: 1.0035x; 1.0035x over previous
//
#include <hip/hip_runtime.h>
#include <hip/hip_cooperative_groups.h>
namespace cg = cooperative_groups;

#define N_NEUR 512
#define B_SZ   16
#define T_STEPS 32
#define NIN    32
#define NOUT   16
#define CAPC   84   // chem nnz/row cap (mean 48.6, sd 6.63)
#define CAPG   52   // gj nnz/row cap   (mean 25.6, sd 4.93)
#define MC     42   // per-thread chem entries (h splits CSR evens/odds)
#define MG     26
#define MCP    21   // packed col words per thread
#define MGP    13
#define NWAVE  16   // waves per block
#define LOG2E  1.4426950408889634f

__device__ __forceinline__ float rcp_fast(float x) {
#if __has_builtin(__builtin_amdgcn_rcpf)
    return __builtin_amdgcn_rcpf(x);
#else
    return 1.0f / x;
#endif
}
__device__ __forceinline__ float exp2_fast(float x) {
#if __has_builtin(__builtin_amdgcn_exp2f)
    return __builtin_amdgcn_exp2f(x);
#else
    return exp2f(x);
#endif
}
// cross-pair sum WITHOUT the DS pipe: DPP quad_perm [1,0,3,2]
__device__ __forceinline__ float pair_swap(float x) {
#if __has_builtin(__builtin_amdgcn_mov_dpp)
    return __int_as_float(__builtin_amdgcn_mov_dpp(__float_as_int(x), 0xB1, 0xF, 0xF, true));
#else
    return __shfl_xor(x, 1);
#endif
}

#define CHEM_K(k, A) {                                                      \
    unsigned pk = cpC[(k) >> 1];                                            \
    unsigned off = ((k) & 1) ? (pk >> 16) : (pk & 0xffffu);                 \
    A = fmaf(wC[k], *(const float*)((const char*)ObP + off), A); }

#define CHEM_C4(a) { CHEM_K(a, accA) CHEM_K((a)+1, accB) CHEM_K((a)+2, accA) CHEM_K((a)+3, accB) }

#define GJ_K(k, A) {                                                        \
    unsigned pk = cpG[(k) >> 1];                                            \
    unsigned off = ((k) & 1) ? (pk >> 16) : (pk & 0xffffu);                 \
    float Os = *(const float*)((const char*)ObP + off);                     \
    float f = fmaf(20.0f * LOG2E, Os, cE);                                  \
    float tnh = 1.0f - 2.0f * rcp_fast(1.0f + exp2_fast(f));                \
    A = fmaf(wG[k] * Os, tnh, A); }

#define GJ_C4(a) { GJ_K(a, accA) GJ_K((a)+1, accB) GJ_K((a)+2, accA) GJ_K((a)+3, accB) }

// ONE cooperative kernel, 16 blocks x 1024 threads:
//  Phase A: distributed prep (softplus+mask+ballot-compact), 2 rows/wave.
//  grid.sync
//  Phase B: block-local ranks in LDS; per-wave layout of its 2 rows
//           (round-0 rank-sort by bank-stagger key; transposed global arrays).
//  grid.sync
//  Phase C: the recurrence (identical to the 103.7us round-0 recur_kernel;
//           runtime ping-pong index, NO t-unroll -- stays within the
//           128-reg/wave budget that round 1 proved is exactly saturated).
__global__ __launch_bounds__(1024, 1) void fused_kernel(
    const float* __restrict__ obs,
    const float* __restrict__ W,
    const float* __restrict__ thr,
    const float* __restrict__ dec,
    const float* __restrict__ mex,
    const float* __restrict__ min_,
    const float* __restrict__ mgj,
    float* __restrict__ out,
    char* __restrict__ ws)
{
    // workspace carve-up (matches launcher)
    int*      key_arr = (int*)(ws);
    int*      ccA     = (int*)(ws + 2048);
    int*      cgA     = (int*)(ws + 4096);
    int2*     tmpC    = (int2*)(ws + 8192);                // 512*84*8 = 344064
    int2*     tmpG    = (int2*)(ws + 8192 + 344064);       // 512*52*8 = 212992
    float*    wCt     = (float*)(ws + 565248);             // 16*42*64*4
    unsigned* cpCt    = (unsigned*)(ws + 737280);          // 16*21*64*4
    float*    wGt     = (float*)(ws + 823296);             // 16*26*64*4
    unsigned* cpGt    = (unsigned*)(ws + 929792);          // 16*13*64*4

    __shared__ float Ob[2][N_NEUR];
    __shared__ float Eb[2][N_NEUR];
    __shared__ int   keyS[N_NEUR];
    __shared__ int   orderS[N_NEUR];
    __shared__ int   rankS[N_NEUR];
    // per-wave prep scratch (16 waves work on independent rows)
    __shared__ int   pcC[NWAVE][CAPC]; __shared__ float pwC[NWAVE][CAPC];
    __shared__ int   pcG[NWAVE][CAPG]; __shared__ float pwG[NWAVE][CAPG];
    __shared__ int   pkey[NWAVE][MC];
    __shared__ int   pscol[NWAVE][MC]; __shared__ float psw[NWAVE][MC];

    cg::grid_group grid = cg::this_grid();

    const int b    = blockIdx.x;
    const int tid  = threadIdx.x;
    const int wv   = tid >> 6;
    const int lane = tid & 63;

    // ---------------- Phase A: prep1 (2 rows per wave) ----------------
    int ccR[2], cgR[2];
    {
        const unsigned long long below = (1ull << lane) - 1ull;
        const int g = b * NWAVE + wv;           // 0..255
        for (int rr = 0; rr < 2; ++rr) {
            const int row = 2 * g + rr;         // 0..511, unique across grid
            int bc = 0, bg = 0;
            for (int c0 = 0; c0 < N_NEUR; c0 += 64) {
                const int col = c0 + lane;
                const int off = row * N_NEUR + col;
                const float w  = W[off];
                const float sp = fmaxf(w, 0.0f) + log1pf(__expf(-fabsf(w)));
                const float dm = mex[off] - min_[off];          // in {-1,0,1}
                bool a = (dm != 0.0f);
                unsigned long long m = __ballot(a);
                int idx = bc + __popcll(m & below);
                if (a && idx < CAPC)
                    tmpC[row * CAPC + idx] = make_int2(col, __float_as_int(sp * dm));
                bc += __popcll(m);

                const float gj = mgj[off];
                bool ag = (gj != 0.0f);
                m = __ballot(ag);
                idx = bg + __popcll(m & below);
                if (ag && idx < CAPG)
                    tmpG[row * CAPG + idx] = make_int2(col, __float_as_int(sp * gj));
                bg += __popcll(m);
            }
            ccR[rr] = min(bc, CAPC); cgR[rr] = min(bg, CAPG);
            if (lane == 0) {
                ccA[row] = ccR[rr]; cgA[row] = cgR[rr];
                key_arr[row] = ccR[rr] + cgR[rr];
            }
        }
    }
    grid.sync();

    // ---------------- Phase B1: block-local ranks ----------------
    if (tid < N_NEUR) keyS[tid] = key_arr[tid];
    __syncthreads();
    if (tid < N_NEUR) {
        const int kd = keyS[tid];
        int r = 0;
        #pragma unroll 8
        for (int j = 0; j < N_NEUR; ++j) {      // uniform j -> LDS broadcast
            int kj = keyS[j];
            r += (kj < kd) || (kj == kd && j < tid);
        }
        orderS[r] = tid;
        rankS[tid] = r;
    }
    __syncthreads();

    // ---------------- Phase B2: layout (round-0 prep2 logic, per wave) ----
    {
        const int g = b * NWAVE + wv;
        for (int rr = 0; rr < 2; ++rr) {
            const int row = 2 * g + rr;
            const int r   = rankS[row];
            const int wvT = r >> 5;
            const int Lb  = 2 * (r & 31);
            const int cc  = ccR[rr], cgj = cgR[rr];

            for (int k = lane; k < CAPC; k += 64) {
                int2 e = (k < cc) ? tmpC[row * CAPC + k] : make_int2(0, 0);
                pcC[wv][k] = e.x; pwC[wv][k] = __int_as_float(e.y);
            }
            for (int k = lane; k < CAPG; k += 64) {
                int2 e = (k < cgj) ? tmpG[row * CAPG + k] : make_int2(0, 0);
                pcG[wv][k] = e.x; pwG[wv][k] = __int_as_float(e.y);
            }
            __syncthreads();                     // uniform trip count: all waves

            #pragma unroll
            for (int task = 0; task < 4; ++task) {   // {chem,gj} x {h0,h1}
                const int isG  = task >> 1, h = task & 1;
                const int cnt  = isG ? cgj : cc;
                const int m    = (cnt + 1 - h) >> 1;
                const int Mcap = isG ? MG : MC;
                const int MPc  = isG ? MGP : MCP;
                const int myL  = Lb + h;

                int col = 0; float wgt = 0.0f; int key = 0;
                if (lane < m) {                  // lane k owns CSR entry 2k+h
                    col = isG ? pcG[wv][2 * lane + h] : pcC[wv][2 * lane + h];
                    wgt = isG ? pwG[wv][2 * lane + h] : pwC[wv][2 * lane + h];
                    key = ((col & 31) - myL) & 31;
                    pkey[wv][lane] = key;
                }
                __syncthreads();
                if (lane < m) {                  // stable rank sort by key
                    int rk = 0;
                    for (int j = 0; j < m; ++j) {
                        int kj = pkey[wv][j];
                        rk += (kj < key) || (kj == key && j < lane);
                    }
                    pscol[wv][rk] = col; psw[wv][rk] = wgt;
                }
                __syncthreads();
                float*    wT = isG ? wGt  : wCt;
                unsigned* cT = isG ? cpGt : cpCt;
                if (lane < Mcap)
                    wT[(wvT * Mcap + lane) * 64 + myL] = (lane < m) ? psw[wv][lane] : 0.0f;
                if (lane < MPc) {
                    unsigned c0 = (2 * lane     < m) ? ((unsigned)pscol[wv][2 * lane]     << 2) : 0u;
                    unsigned c1 = (2 * lane + 1 < m) ? ((unsigned)pscol[wv][2 * lane + 1] << 2) : 0u;
                    cT[(wvT * MPc + lane) * 64 + myL] = c0 | (c1 << 16);
                }
                __syncthreads();                 // scratch reused next task
            }
        }
    }
    grid.sync();

    // ---------------- Phase C: recurrence (round-0 recur_kernel) ----------
    const int h = tid & 1;
    const int r = tid >> 1;                     // rank

    const int d = orderS[r];
    const int cc = ccA[d];
    const int cgj = cgA[d];
    const float thr_d = thr[d];
    const float dec_d = dec[d];

    int ccw = cc, cgw = cgj;
    #pragma unroll
    for (int i = 1; i < 64; i <<= 1) {
        ccw = max(ccw, __shfl_xor(ccw, i));
        cgw = max(cgw, __shfl_xor(cgw, i));
    }
    const int mCw = __builtin_amdgcn_readfirstlane((ccw + 1) >> 1);
    const int mGw = __builtin_amdgcn_readfirstlane((cgw + 1) >> 1);

    // register-resident lists (zero-padded; padding cols are 0 -> broadcast)
    float wC[MC]; unsigned cpC[MCP];
    float wG[MG]; unsigned cpG[MGP];
    #pragma unroll
    for (int k = 0; k < MC; ++k)  wC[k]  = wCt[(wv * MC + k) * 64 + lane];
    #pragma unroll
    for (int k = 0; k < MCP; ++k) cpC[k] = cpCt[(wv * MCP + k) * 64 + lane];
    #pragma unroll
    for (int k = 0; k < MG; ++k)  wG[k]  = wGt[(wv * MG + k) * 64 + lane];
    #pragma unroll
    for (int k = 0; k < MGP; ++k) cpG[k] = cpGt[(wv * MGP + k) * 64 + lane];

    const bool inj = (h == 0) && (d < NIN);
    const bool wr  = (h == 0) && (d >= NIN) && (d < NIN + NOUT);
    float* outp = out + (size_t)b * T_STEPS * NOUT + (d - NIN);
    const float* obs_b = obs + b * (T_STEPS * NIN);

    if (h == 0) {
        float v = (d < NIN) ? obs_b[d] : 0.0f;   // state 0 = zeros + obs_0
        Ob[0][d] = v;
        Eb[0][d] = v;
    }
    int p = 0;
    __syncthreads();

    for (int t = 0; t < T_STEPS; ++t) {
        // prefetch obs_{t+1} (written into the next buffer at step's end)
        float ob_next = (inj && (t + 1 < T_STEPS)) ? obs_b[(t + 1) * NIN + d] : 0.0f;

        const float* ObP = Ob[p];
        const float E_d = Eb[p][d];
        float accA = 0.0f, accB = 0.0f;
        // chem: chunks of 4, wave-uniform scalar guards, constant reg indices
        CHEM_C4(0)
        if ( 4 < mCw) CHEM_C4(4)
        if ( 8 < mCw) CHEM_C4(8)
        if (12 < mCw) CHEM_C4(12)
        if (16 < mCw) CHEM_C4(16)
        if (20 < mCw) CHEM_C4(20)
        if (24 < mCw) CHEM_C4(24)
        if (28 < mCw) CHEM_C4(28)
        if (32 < mCw) CHEM_C4(32)
        if (36 < mCw) CHEM_C4(36)
        if (40 < mCw) { CHEM_K(40, accA) CHEM_K(41, accB) }
        // gj
        const float cE = -20.0f * LOG2E * E_d;
        GJ_C4(0)
        if ( 4 < mGw) GJ_C4(4)
        if ( 8 < mGw) GJ_C4(8)
        if (12 < mGw) GJ_C4(12)
        if (16 < mGw) GJ_C4(16)
        if (20 < mGw) GJ_C4(20)
        if (24 < mGw) { GJ_K(24, accA) GJ_K(25, accB) }

        float acc = accA + accB;
        acc += pair_swap(acc);

        // epilogue (both halves compute; h==0 writes)
        float curr = fminf(fmaxf(E_d + acc, -10.0f), 10.0f);
        float z = curr - thr_d;
        float O_new = (z >= 0.0f) ? z : 0.01f * z;
        float fg = rcp_fast(1.0f + exp2_fast(-10.0f * LOG2E * z));
        float dg = rcp_fast(1.0f + exp2_fast(-5.0f * LOG2E * (fabsf(E_d - curr) - 0.01f)));
        float E_nf  = dg * curr + (1.0f - dg) * (E_d - dec_d);
        float E_new = fg * O_new + (1.0f - fg) * E_nf;

        const int q = p ^ 1;
        if (h == 0) {
            Eb[q][d] = inj ? ob_next : E_new;
            Ob[q][d] = inj ? ob_next : O_new;
            if (wr) outp[t * NOUT] = E_new;
        }
        __syncthreads();
        p = q;
    }
}

extern "C" void kernel_launch(void* const* d_in, const int* in_sizes, int n_in,
                              void* d_out, int out_size, void* d_ws, size_t ws_size,
                              hipStream_t stream)
{
    const float* obs  = (const float*)d_in[0];
    const float* W    = (const float*)d_in[1];
    const float* thr  = (const float*)d_in[2];
    const float* dec  = (const float*)d_in[3];
    const float* mex  = (const float*)d_in[4];
    const float* min_ = (const float*)d_in[5];
    const float* mgj  = (const float*)d_in[6];
    float* out = (float*)d_out;
    char* ws = (char*)d_ws;   // ~983 KB used, layout inside kernel

    void* args[] = {
        (void*)&obs, (void*)&W, (void*)&thr, (void*)&dec,
        (void*)&mex, (void*)&min_, (void*)&mgj, (void*)&out, (void*)&ws
    };
    hipLaunchCooperativeKernel((const void*)fused_kernel,
                               dim3(B_SZ), dim3(1024), args, 0, stream);
}

// Round 3
// 214.684 us; speedup vs baseline: 1.1913x; 1.1872x over previous
//
#include <hip/hip_runtime.h>

#define N_NEUR 512
#define B_SZ   16
#define T_STEPS 32
#define NIN    32
#define NOUT   16
#define CAPC   84   // chem nnz/row cap (mean 48.6, sd 6.63)
#define CAPG   52   // gj nnz/row cap   (mean 25.6, sd 4.93)
#define MC     42   // per-thread chem entries (h splits CSR evens/odds)
#define MG     26
#define MCP    21   // packed col words per thread
#define MGP    13
#define SLACKC 6    // placement slack (trips beyond per-wave half-list max)
#define SLACKG 6
#define LOG2E  1.4426950408889634f

__device__ __forceinline__ float rcp_fast(float x) {
#if __has_builtin(__builtin_amdgcn_rcpf)
    return __builtin_amdgcn_rcpf(x);
#else
    return 1.0f / x;
#endif
}
__device__ __forceinline__ float exp2_fast(float x) {
#if __has_builtin(__builtin_amdgcn_exp2f)
    return __builtin_amdgcn_exp2f(x);
#else
    return exp2f(x);
#endif
}
// cross-pair sum WITHOUT the DS pipe: DPP quad_perm [1,0,3,2]
__device__ __forceinline__ float pair_swap(float x) {
#if __has_builtin(__builtin_amdgcn_mov_dpp)
    return __int_as_float(__builtin_amdgcn_mov_dpp(__float_as_int(x), 0xB1, 0xF, 0xF, true));
#else
    return __shfl_xor(x, 1);
#endif
}

// prep1: per row, softplus + mask + ballot-compact into dense per-row tmp CSR.
__global__ __launch_bounds__(64) void prep1_kernel(
    const float* __restrict__ W,
    const float* __restrict__ mex,
    const float* __restrict__ min_,
    const float* __restrict__ mgj,
    int* __restrict__ key_arr, int* __restrict__ ccA, int* __restrict__ cgA,
    int2* __restrict__ tmpC, int2* __restrict__ tmpG)
{
    const int row  = blockIdx.x;
    const int lane = threadIdx.x;
    const unsigned long long below = (1ull << lane) - 1ull;
    int bc = 0, bg = 0;
    for (int c0 = 0; c0 < N_NEUR; c0 += 64) {
        const int col = c0 + lane;
        const int off = row * N_NEUR + col;
        const float w  = W[off];
        const float sp = fmaxf(w, 0.0f) + log1pf(__expf(-fabsf(w)));  // softplus
        const float dm = mex[off] - min_[off];                         // in {-1,0,1}
        bool a = (dm != 0.0f);
        unsigned long long m = __ballot(a);
        int idx = bc + __popcll(m & below);
        if (a && idx < CAPC)
            tmpC[row * CAPC + idx] = make_int2(col, __float_as_int(sp * dm));
        bc += __popcll(m);

        const float g = mgj[off];
        bool ag = (g != 0.0f);
        m = __ballot(ag);
        idx = bg + __popcll(m & below);
        if (ag && idx < CAPG)
            tmpG[row * CAPG + idx] = make_int2(col, __float_as_int(sp * g));
        bg += __popcll(m);
    }
    if (lane == 0) {
        int cc = min(bc, CAPC), cg = min(bg, CAPG);
        ccA[row] = cc; cgA[row] = cg; key_arr[row] = cc + cg;
    }
}

// rank_kernel: single block, 512 threads. Global sort ranks (asc by nnz),
// order array, and PADDED per-wave trip counts: M = min(cap, halfmax +
// SLACK, rounded up to x4). The slack is what round 1 was missing -- it
// gives the slot placement in prep2 the freedom to bank-align entries.
__global__ __launch_bounds__(512) void rank_kernel(
    int* __restrict__ key_then_rank,          // in: key, out: rank
    const int* __restrict__ ccA, const int* __restrict__ cgA,
    int* __restrict__ order, int* __restrict__ mCwA, int* __restrict__ mGwA)
{
    __shared__ int keyS[N_NEUR];
    __shared__ int mxc[16], mxg[16];
    const int d = threadIdx.x;
    keyS[d] = key_then_rank[d];
    if (d < 16) { mxc[d] = 0; mxg[d] = 0; }
    __syncthreads();
    const int kd = keyS[d];
    int r = 0;
    #pragma unroll 8
    for (int j = 0; j < N_NEUR; ++j) {        // same j across lanes -> LDS broadcast
        int kj = keyS[j];
        r += (kj < kd) || (kj == kd && j < d);
    }
    order[r] = d;
    key_then_rank[d] = r;
    atomicMax(&mxc[r >> 5], ccA[d]);
    atomicMax(&mxg[r >> 5], cgA[d]);
    __syncthreads();
    if (d < 16) {
        int mc = ((mxc[d] + 1) >> 1) + SLACKC;
        mc = (mc + 3) & ~3;                   // x4 so recur's guards cover exactly M
        mCwA[d] = min(mc, MC);
        int mg = ((mxg[d] + 1) >> 1) + SLACKG;
        mg = (mg + 3) & ~3;
        mGwA[d] = min(mg, MG);
    }
}

// prep2: per row, split CSR into evens/odds (h); sort each half-list by the
// bank-stagger key ((col&31)-myL)&31; VALUE-PLACED SLOT SCHEDULING with
// slack: entry with key kappa -> slot ~ kappa*M/32 (M = padded per-wave trip
// count), injectivity repaired by prefix-max + cap clamp. Empty slots get
// BANK-ALIGNED dummies (offset 4*((k*32/M + myL)&31), weight 0) so padding
// reads land on the same bank schedule instead of piling onto bank 0.
// Result: at slot k all 64 lanes hit bank ~ (32k/M + lane)&31 -> ~2-way
// (free) regardless of ragged list lengths.
__global__ __launch_bounds__(64) void prep2_kernel(
    const int* __restrict__ rankA, const int* __restrict__ ccA, const int* __restrict__ cgA,
    const int* __restrict__ mCwA, const int* __restrict__ mGwA,
    const int2* __restrict__ tmpC, const int2* __restrict__ tmpG,
    float* __restrict__ wCt, unsigned* __restrict__ cpCt,
    float* __restrict__ wGt, unsigned* __restrict__ cpGt)
{
    __shared__ int   cS[CAPC];  __shared__ float wS[CAPC];
    __shared__ int   cSg[CAPG]; __shared__ float wSg[CAPG];
    __shared__ int   keyS[MC];
    __shared__ int   scol[MC];  __shared__ float sw[MC];
    __shared__ float wOut[MC];  __shared__ int   oOut[MC];
    const int d    = blockIdx.x;
    const int lane = threadIdx.x;
    const int r    = rankA[d];
    const int wv   = r >> 5;
    const int Lb   = 2 * (r & 31);
    const int cc = ccA[d], cg = cgA[d];
    const int Mc = mCwA[wv], Mg = mGwA[wv];

    for (int k = lane; k < CAPC; k += 64) {
        int2 e = (k < cc) ? tmpC[d * CAPC + k] : make_int2(0, 0);
        cS[k] = e.x; wS[k] = __int_as_float(e.y);
    }
    for (int k = lane; k < CAPG; k += 64) {
        int2 e = (k < cg) ? tmpG[d * CAPG + k] : make_int2(0, 0);
        cSg[k] = e.x; wSg[k] = __int_as_float(e.y);
    }
    __syncthreads();

    #pragma unroll
    for (int task = 0; task < 4; ++task) {   // {chem,gj} x {h0,h1}
        const int isG  = task >> 1, h = task & 1;
        const int cnt  = isG ? cg : cc;
        const int m    = (cnt + 1 - h) >> 1;  // entries in this half-list (m <= M)
        const int M    = isG ? Mg : Mc;       // padded per-wave trip count
        const int Mcap = isG ? MG : MC;
        const int MPc  = isG ? MGP : MCP;
        const int myL  = Lb + h;              // owner lane in the main kernel

        int col = 0; float w = 0.0f; int key = 0;
        if (lane < m) {                       // lane k owns CSR entry 2k+h
            col = isG ? cSg[2 * lane + h] : cS[2 * lane + h];
            w   = isG ? wSg[2 * lane + h] : wS[2 * lane + h];
            key = ((col & 31) - myL) & 31;
            keyS[lane] = key;
        }
        __syncthreads();
        if (lane < m) {                       // stable rank sort by key
            int rk = 0;
            for (int j = 0; j < m; ++j) {
                int kj = keyS[j];
                rk += (kj < key) || (kj == key && j < lane);
            }
            scol[rk] = col; sw[rk] = w;
        }
        if (lane < Mcap) {                    // bank-aligned dummy fill
            wOut[lane] = 0.0f;
            int bk = (((lane * 32) / M) + myL) & 31;
            oOut[lane] = bk << 2;
        }
        __syncthreads();

        // value placement on sorted entries: desired slot d_j = key_j*M/32;
        // repair to strictly increasing via s_j = j + prefmax(d_i - i),
        // clamp to the feasibility cap M-m+j.
        int a = -(1 << 28);
        int colj = 0; float wj = 0.0f;
        if (lane < m) {
            colj = scol[lane]; wj = sw[lane];
            int kj = ((colj & 31) - myL) & 31;
            a = ((kj * M) >> 5) - lane;
        }
        #pragma unroll
        for (int o = 1; o < 64; o <<= 1) {
            int t2 = __shfl_up(a, o);
            if (lane >= o) a = max(a, t2);
        }
        if (lane < m) {
            int slot = min(lane + a, M - m + lane);
            wOut[slot] = wj;
            oOut[slot] = colj << 2;           // byte offset
        }
        __syncthreads();

        float*    wT = isG ? wGt  : wCt;
        unsigned* cT = isG ? cpGt : cpCt;
        if (lane < Mcap)
            wT[(wv * Mcap + lane) * 64 + myL] = wOut[lane];
        if (lane < MPc) {
            unsigned c0 = (unsigned)oOut[2 * lane];
            unsigned c1 = (unsigned)oOut[2 * lane + 1];
            cT[(wv * MPc + lane) * 64 + myL] = c0 | (c1 << 16);
        }
        __syncthreads();                      // scratch reused next task
    }
}

#define CHEM_K(k, A) {                                                      \
    unsigned pk = cpC[(k) >> 1];                                            \
    unsigned off = ((k) & 1) ? (pk >> 16) : (pk & 0xffffu);                 \
    A = fmaf(wC[k], *(const float*)((const char*)ObP + off), A); }

#define CHEM_C4(a) { CHEM_K(a, accA) CHEM_K((a)+1, accB) CHEM_K((a)+2, accA) CHEM_K((a)+3, accB) }

#define GJ_K(k, A) {                                                        \
    unsigned pk = cpG[(k) >> 1];                                            \
    unsigned off = ((k) & 1) ? (pk >> 16) : (pk & 0xffffu);                 \
    float Os = *(const float*)((const char*)ObP + off);                     \
    float f = fmaf(20.0f * LOG2E, Os, cE);                                  \
    float tnh = 1.0f - 2.0f * rcp_fast(1.0f + exp2_fast(f));                \
    A = fmaf(wG[k] * Os, tnh, A); }

#define GJ_C4(a) { GJ_K(a, accA) GJ_K((a)+1, accB) GJ_K((a)+2, accA) GJ_K((a)+3, accB) }

// main: one block per batch, 1024 threads = 2 per neuron (sorted by nnz).
// Round-0 body exactly (runtime ping-pong p, no t-unroll -- the 128-reg/wave
// budget is saturated; round 1 proved any live-range growth spills), with
// trip counts from rank_kernel (matches prep2's slot layout) and the DS-pipe
// shfl replaced by a VALU DPP swap.
__global__ __launch_bounds__(1024, 1) void recur_kernel(
    const float* __restrict__ obs,
    const float* __restrict__ thr,
    const float* __restrict__ dec,
    const int* __restrict__ order,
    const int* __restrict__ mCwA, const int* __restrict__ mGwA,
    const float* __restrict__ wCt, const unsigned* __restrict__ cpCt,
    const float* __restrict__ wGt, const unsigned* __restrict__ cpGt,
    float* __restrict__ out)
{
    __shared__ float Ob[2][N_NEUR];
    __shared__ float Eb[2][N_NEUR];

    const int b    = blockIdx.x;
    const int tid  = threadIdx.x;
    const int h    = tid & 1;
    const int r    = tid >> 1;            // rank
    const int wv   = tid >> 6;
    const int lane = tid & 63;

    const int d = order[r];
    const float thr_d = thr[d];
    const float dec_d = dec[d];

    const int mCw = __builtin_amdgcn_readfirstlane(mCwA[wv]);
    const int mGw = __builtin_amdgcn_readfirstlane(mGwA[wv]);

    // register-resident lists (padding slots: w=0, bank-aligned offsets)
    float wC[MC]; unsigned cpC[MCP];
    float wG[MG]; unsigned cpG[MGP];
    #pragma unroll
    for (int k = 0; k < MC; ++k)  wC[k]  = wCt[(wv * MC + k) * 64 + lane];
    #pragma unroll
    for (int k = 0; k < MCP; ++k) cpC[k] = cpCt[(wv * MCP + k) * 64 + lane];
    #pragma unroll
    for (int k = 0; k < MG; ++k)  wG[k]  = wGt[(wv * MG + k) * 64 + lane];
    #pragma unroll
    for (int k = 0; k < MGP; ++k) cpG[k] = cpGt[(wv * MGP + k) * 64 + lane];

    const bool inj = (h == 0) && (d < NIN);
    const bool wr  = (h == 0) && (d >= NIN) && (d < NIN + NOUT);
    float* outp = out + (size_t)b * T_STEPS * NOUT + (d - NIN);
    const float* obs_b = obs + b * (T_STEPS * NIN);

    if (h == 0) {
        float v = (d < NIN) ? obs_b[d] : 0.0f;   // state 0 = zeros + obs_0
        Ob[0][d] = v;
        Eb[0][d] = v;
    }
    int p = 0;
    __syncthreads();

    for (int t = 0; t < T_STEPS; ++t) {
        // prefetch obs_{t+1} (written into the next buffer at this step's end)
        float ob_next = (inj && (t + 1 < T_STEPS)) ? obs_b[(t + 1) * NIN + d] : 0.0f;

        const float* ObP = Ob[p];
        const float E_d = Eb[p][d];
        float accA = 0.0f, accB = 0.0f;
        // chem: chunks of 4, wave-uniform scalar guards, constant reg indices
        CHEM_C4(0)
        if ( 4 < mCw) CHEM_C4(4)
        if ( 8 < mCw) CHEM_C4(8)
        if (12 < mCw) CHEM_C4(12)
        if (16 < mCw) CHEM_C4(16)
        if (20 < mCw) CHEM_C4(20)
        if (24 < mCw) CHEM_C4(24)
        if (28 < mCw) CHEM_C4(28)
        if (32 < mCw) CHEM_C4(32)
        if (36 < mCw) CHEM_C4(36)
        if (40 < mCw) { CHEM_K(40, accA) CHEM_K(41, accB) }
        // gj
        const float cE = -20.0f * LOG2E * E_d;
        GJ_C4(0)
        if ( 4 < mGw) GJ_C4(4)
        if ( 8 < mGw) GJ_C4(8)
        if (12 < mGw) GJ_C4(12)
        if (16 < mGw) GJ_C4(16)
        if (20 < mGw) GJ_C4(20)
        if (24 < mGw) { GJ_K(24, accA) GJ_K(25, accB) }

        float acc = accA + accB;
        acc += pair_swap(acc);

        // epilogue (both halves compute; h==0 writes)
        float curr = fminf(fmaxf(E_d + acc, -10.0f), 10.0f);
        float z = curr - thr_d;
        float O_new = (z >= 0.0f) ? z : 0.01f * z;
        float fg = rcp_fast(1.0f + exp2_fast(-10.0f * LOG2E * z));
        float dg = rcp_fast(1.0f + exp2_fast(-5.0f * LOG2E * (fabsf(E_d - curr) - 0.01f)));
        float E_nf  = dg * curr + (1.0f - dg) * (E_d - dec_d);
        float E_new = fg * O_new + (1.0f - fg) * E_nf;

        const int q = p ^ 1;
        if (h == 0) {
            Eb[q][d] = inj ? ob_next : E_new;
            Ob[q][d] = inj ? ob_next : O_new;
            if (wr) outp[t * NOUT] = E_new;
        }
        __syncthreads();
        p = q;
    }
}

extern "C" void kernel_launch(void* const* d_in, const int* in_sizes, int n_in,
                              void* d_out, int out_size, void* d_ws, size_t ws_size,
                              hipStream_t stream)
{
    const float* obs  = (const float*)d_in[0];
    const float* W    = (const float*)d_in[1];
    const float* thr  = (const float*)d_in[2];
    const float* dec  = (const float*)d_in[3];
    const float* mex  = (const float*)d_in[4];
    const float* min_ = (const float*)d_in[5];
    const float* mgj  = (const float*)d_in[6];
    float* out = (float*)d_out;

    char* ws = (char*)d_ws;
    int*   key_arr = (int*)(ws);                           // then rank (in place)
    int*   ccA     = (int*)(ws + 2048);
    int*   cgA     = (int*)(ws + 4096);
    int*   order   = (int*)(ws + 6144);
    int2*  tmpC    = (int2*)(ws + 8192);                   // 512*84*8 = 344064
    int2*  tmpG    = (int2*)(ws + 8192 + 344064);          // 512*52*8 = 212992
    float* wCt     = (float*)(ws + 565248);                // 16*42*64*4 = 172032
    unsigned* cpCt = (unsigned*)(ws + 737280);             // 16*21*64*4 =  86016
    float* wGt     = (float*)(ws + 823296);                // 16*26*64*4 = 106496
    unsigned* cpGt = (unsigned*)(ws + 929792);             // 16*13*64*4 =  53248
    int*   mCwA    = (int*)(ws + 983040);                  // 16*4
    int*   mGwA    = (int*)(ws + 983104);                  // 16*4
    // total ws use: ~983.2 KB

    prep1_kernel<<<N_NEUR, 64, 0, stream>>>(W, mex, min_, mgj,
                                            key_arr, ccA, cgA, tmpC, tmpG);
    rank_kernel<<<1, 512, 0, stream>>>(key_arr, ccA, cgA, order, mCwA, mGwA);
    prep2_kernel<<<N_NEUR, 64, 0, stream>>>(key_arr, ccA, cgA, mCwA, mGwA,
                                            tmpC, tmpG, wCt, cpCt, wGt, cpGt);
    recur_kernel<<<B_SZ, 1024, 0, stream>>>(obs, thr, dec,
                                            order, mCwA, mGwA,
                                            wCt, cpCt, wGt, cpGt, out);
}

// Round 4
// 198.419 us; speedup vs baseline: 1.2890x; 1.0820x over previous
//
#include <hip/hip_runtime.h>

#define N_NEUR 512
#define B_SZ   16
#define T_STEPS 32
#define NIN    32
#define NOUT   16
#define CAPC   84   // chem nnz/row cap (mean 48.6, sd 6.63)
#define CAPG   52   // gj nnz/row cap   (mean 25.6, sd 4.93)
#define MC     42   // per-thread chem trips (h splits CSR evens/odds)
#define MG     26
#define MCP    21   // trip PAIRS per thread (float2 weights / packed cols)
#define MGP    13
#define LOG2E  1.4426950408889634f

__device__ __forceinline__ float rcp_fast(float x) {
#if __has_builtin(__builtin_amdgcn_rcpf)
    return __builtin_amdgcn_rcpf(x);
#else
    return 1.0f / x;
#endif
}
__device__ __forceinline__ float exp2_fast(float x) {
#if __has_builtin(__builtin_amdgcn_exp2f)
    return __builtin_amdgcn_exp2f(x);
#else
    return exp2f(x);
#endif
}
// cross-pair sum WITHOUT the DS pipe: DPP quad_perm [1,0,3,2]
__device__ __forceinline__ float pair_swap(float x) {
#if __has_builtin(__builtin_amdgcn_mov_dpp)
    return __int_as_float(__builtin_amdgcn_mov_dpp(__float_as_int(x), 0xB1, 0xF, 0xF, true));
#else
    return __shfl_xor(x, 1);
#endif
}

// prep1: per row, softplus + mask + ballot-compact into dense per-row tmp CSR.
__global__ __launch_bounds__(64) void prep1_kernel(
    const float* __restrict__ W,
    const float* __restrict__ mex,
    const float* __restrict__ min_,
    const float* __restrict__ mgj,
    int* __restrict__ key_arr, int* __restrict__ ccA, int* __restrict__ cgA,
    int2* __restrict__ tmpC, int2* __restrict__ tmpG)
{
    const int row  = blockIdx.x;
    const int lane = threadIdx.x;
    const unsigned long long below = (1ull << lane) - 1ull;
    int bc = 0, bg = 0;
    for (int c0 = 0; c0 < N_NEUR; c0 += 64) {
        const int col = c0 + lane;
        const int off = row * N_NEUR + col;
        const float w  = W[off];
        const float sp = fmaxf(w, 0.0f) + log1pf(__expf(-fabsf(w)));  // softplus
        const float dm = mex[off] - min_[off];                         // in {-1,0,1}
        bool a = (dm != 0.0f);
        unsigned long long m = __ballot(a);
        int idx = bc + __popcll(m & below);
        if (a && idx < CAPC)
            tmpC[row * CAPC + idx] = make_int2(col, __float_as_int(sp * dm));
        bc += __popcll(m);

        const float g = mgj[off];
        bool ag = (g != 0.0f);
        m = __ballot(ag);
        idx = bg + __popcll(m & below);
        if (ag && idx < CAPG)
            tmpG[row * CAPG + idx] = make_int2(col, __float_as_int(sp * g));
        bg += __popcll(m);
    }
    if (lane == 0) {
        int cc = min(bc, CAPC), cg = min(bg, CAPG);
        ccA[row] = cc; cgA[row] = cg; key_arr[row] = cc + cg;
    }
}

// prep2: (round-0 structure) per row: rank among all rows by nnz (asc);
// split CSR into evens/odds (h); bank-stagger rank-sort each half-list;
// emit transposed layout -- weights as float2 TRIP PAIRS (streamed from
// global by recur), packed byte-offset col pairs in cpT.
__global__ __launch_bounds__(64) void prep2_kernel(
    const int* __restrict__ key_arr, const int* __restrict__ ccA, const int* __restrict__ cgA,
    const int2* __restrict__ tmpC, const int2* __restrict__ tmpG,
    int* __restrict__ order,
    float2* __restrict__ wCt, unsigned* __restrict__ cpCt,
    float2* __restrict__ wGt, unsigned* __restrict__ cpGt)
{
    __shared__ int   cS[CAPC];  __shared__ float wS[CAPC];
    __shared__ int   cSg[CAPG]; __shared__ float wSg[CAPG];
    __shared__ int   keyS[MC];
    __shared__ int   scol[MC];  __shared__ float sw[MC];
    const int d    = blockIdx.x;
    const int lane = threadIdx.x;
    const int kd   = key_arr[d];
    int r = 0;
    for (int j = lane; j < N_NEUR; j += 64) {
        int kj = key_arr[j];
        r += (kj < kd) || (kj == kd && j < d);
    }
    #pragma unroll
    for (int i = 1; i < 64; i <<= 1) r += __shfl_xor(r, i);
    if (lane == 0) order[r] = d;

    const int wv = r >> 5;            // main tid = 2r+h -> wv = r>>5
    const int Lb = 2 * (r & 31);
    const int cc = ccA[d], cg = cgA[d];

    for (int k = lane; k < CAPC; k += 64) {
        int2 e = (k < cc) ? tmpC[d * CAPC + k] : make_int2(0, 0);
        cS[k] = e.x; wS[k] = __int_as_float(e.y);
    }
    for (int k = lane; k < CAPG; k += 64) {
        int2 e = (k < cg) ? tmpG[d * CAPG + k] : make_int2(0, 0);
        cSg[k] = e.x; wSg[k] = __int_as_float(e.y);
    }
    __syncthreads();

    #pragma unroll
    for (int task = 0; task < 4; ++task) {   // {chem,gj} x {h0,h1}
        const int isG = task >> 1, h = task & 1;
        const int cnt = isG ? cg : cc;
        const int m   = (cnt + 1 - h) >> 1;  // entries in this half-list
        const int MP  = isG ? MGP : MCP;     // pairs
        const int myL = Lb + h;              // owner lane in the main kernel

        int col = 0; float w = 0.0f; int key = 0;
        if (lane < m) {                      // lane k owns CSR entry 2k+h
            col = isG ? cSg[2 * lane + h] : cS[2 * lane + h];
            w   = isG ? wSg[2 * lane + h] : wS[2 * lane + h];
            key = ((col & 31) - myL) & 31;
            keyS[lane] = key;
        }
        __syncthreads();
        if (lane < m) {
            int rk = 0;
            for (int j = 0; j < m; ++j) {
                int kj = keyS[j];
                rk += (kj < key) || (kj == key && j < lane);
            }
            scol[rk] = col; sw[rk] = w;
        }
        __syncthreads();
        float2*   wT = isG ? wGt  : wCt;
        unsigned* cT = isG ? cpGt : cpCt;
        if (lane < MP) {
            float2 v;
            v.x = (2 * lane     < m) ? sw[2 * lane]     : 0.0f;
            v.y = (2 * lane + 1 < m) ? sw[2 * lane + 1] : 0.0f;
            wT[(wv * MP + lane) * 64 + myL] = v;
            unsigned c0 = (2 * lane     < m) ? ((unsigned)scol[2 * lane]     << 2) : 0u;
            unsigned c1 = (2 * lane + 1 < m) ? ((unsigned)scol[2 * lane + 1] << 2) : 0u;
            cT[(wv * MP + lane) * 64 + myL] = c0 | (c1 << 16);
        }
        __syncthreads();                     // scol/keyS reused next task
    }
}

// Per trip-pair kp: weights STREAMED from global (L2-resident, VMEM pipe,
// static offset kp*512 folds into the load immediate); col offsets from
// register-resident packed words; O gathered from LDS.
#define CHEM_P(kp) {                                                        \
    unsigned pk = cpC[kp];                                                  \
    float2 wp = wCb[(kp) * 64];                                             \
    accA = fmaf(wp.x, *(const float*)((const char*)ObP + (pk & 0xffffu)), accA); \
    accB = fmaf(wp.y, *(const float*)((const char*)ObP + (pk >> 16)), accB); }

#define GJ_P(kp) {                                                         \
    unsigned pk = cpG[kp];                                                 \
    float2 wp = wGb[(kp) * 64];                                            \
    {   float Os = *(const float*)((const char*)ObP + (pk & 0xffffu));     \
        float f = fmaf(20.0f * LOG2E, Os, cE);                             \
        float tnh = 1.0f - 2.0f * rcp_fast(1.0f + exp2_fast(f));           \
        accA = fmaf(wp.x * Os, tnh, accA); }                               \
    {   float Os = *(const float*)((const char*)ObP + (pk >> 16));         \
        float f = fmaf(20.0f * LOG2E, Os, cE);                             \
        float tnh = 1.0f - 2.0f * rcp_fast(1.0f + exp2_fast(f));           \
        accB = fmaf(wp.y * Os, tnh, accB); } }

// main: one block per batch, 1024 threads = 2 per neuron (sorted by nnz).
// Round-0 structure; ONLY structural change: weight lists are NOT register-
// resident (streamed from global) -- frees ~68 regs so the LDS gathers can
// pipeline instead of serializing at ~1 in flight (round-3 marginal-cost
// measurement: ~103 cyc/trip ~= full ds_read latency).
__global__ __launch_bounds__(1024, 1) void recur_kernel(
    const float* __restrict__ obs,
    const float* __restrict__ thr,
    const float* __restrict__ dec,
    const int* __restrict__ order, const int* __restrict__ ccA, const int* __restrict__ cgA,
    const float2* __restrict__ wCt, const unsigned* __restrict__ cpCt,
    const float2* __restrict__ wGt, const unsigned* __restrict__ cpGt,
    float* __restrict__ out)
{
    __shared__ float Ob[2][N_NEUR];
    __shared__ float Eb[2][N_NEUR];

    const int b    = blockIdx.x;
    const int tid  = threadIdx.x;
    const int h    = tid & 1;
    const int r    = tid >> 1;            // rank
    const int wv   = tid >> 6;
    const int lane = tid & 63;

    const int d = order[r];
    const int cc = ccA[d];
    const int cg = cgA[d];
    const float thr_d = thr[d];
    const float dec_d = dec[d];

    int ccw = cc, cgw = cg;
    #pragma unroll
    for (int i = 1; i < 64; i <<= 1) {
        ccw = max(ccw, __shfl_xor(ccw, i));
        cgw = max(cgw, __shfl_xor(cgw, i));
    }
    const int mCw = __builtin_amdgcn_readfirstlane((ccw + 1) >> 1);
    const int mGw = __builtin_amdgcn_readfirstlane((cgw + 1) >> 1);

    // register-resident packed col offsets (34 words); weights streamed
    unsigned cpC[MCP]; unsigned cpG[MGP];
    #pragma unroll
    for (int k = 0; k < MCP; ++k) cpC[k] = cpCt[(wv * MCP + k) * 64 + lane];
    #pragma unroll
    for (int k = 0; k < MGP; ++k) cpG[k] = cpGt[(wv * MGP + k) * 64 + lane];

    const float2* wCb = wCt + (wv * MCP) * 64 + lane;
    const float2* wGb = wGt + (wv * MGP) * 64 + lane;

    const bool inj = (h == 0) && (d < NIN);
    const bool wr  = (h == 0) && (d >= NIN) && (d < NIN + NOUT);
    float* outp = out + (size_t)b * T_STEPS * NOUT + (d - NIN);
    const float* obs_b = obs + b * (T_STEPS * NIN);

    if (h == 0) {
        float v = (d < NIN) ? obs_b[d] : 0.0f;   // state 0 = zeros + obs_0
        Ob[0][d] = v;
        Eb[0][d] = v;
    }
    int p = 0;
    __syncthreads();

    for (int t = 0; t < T_STEPS; ++t) {
        // prefetch obs_{t+1} (written into the next buffer at this step's end)
        float ob_next = (inj && (t + 1 < T_STEPS)) ? obs_b[(t + 1) * NIN + d] : 0.0f;

        const float* ObP = Ob[p];
        const float E_d = Eb[p][d];
        float accA = 0.0f, accB = 0.0f;
        // chem: pairs of trips; wave-uniform scalar guards at granularity 4
        CHEM_P(0)  CHEM_P(1)
        if ( 4 < mCw) { CHEM_P(2)  CHEM_P(3)  }
        if ( 8 < mCw) { CHEM_P(4)  CHEM_P(5)  }
        if (12 < mCw) { CHEM_P(6)  CHEM_P(7)  }
        if (16 < mCw) { CHEM_P(8)  CHEM_P(9)  }
        if (20 < mCw) { CHEM_P(10) CHEM_P(11) }
        if (24 < mCw) { CHEM_P(12) CHEM_P(13) }
        if (28 < mCw) { CHEM_P(14) CHEM_P(15) }
        if (32 < mCw) { CHEM_P(16) CHEM_P(17) }
        if (36 < mCw) { CHEM_P(18) CHEM_P(19) }
        if (40 < mCw) { CHEM_P(20) }
        // gj
        const float cE = -20.0f * LOG2E * E_d;
        GJ_P(0)  GJ_P(1)
        if ( 4 < mGw) { GJ_P(2)  GJ_P(3)  }
        if ( 8 < mGw) { GJ_P(4)  GJ_P(5)  }
        if (12 < mGw) { GJ_P(6)  GJ_P(7)  }
        if (16 < mGw) { GJ_P(8)  GJ_P(9)  }
        if (20 < mGw) { GJ_P(10) GJ_P(11) }
        if (24 < mGw) { GJ_P(12) }

        float acc = accA + accB;
        acc += pair_swap(acc);

        // epilogue (both halves compute; h==0 writes)
        float curr = fminf(fmaxf(E_d + acc, -10.0f), 10.0f);
        float z = curr - thr_d;
        float O_new = (z >= 0.0f) ? z : 0.01f * z;
        float fg = rcp_fast(1.0f + exp2_fast(-10.0f * LOG2E * z));
        float dg = rcp_fast(1.0f + exp2_fast(-5.0f * LOG2E * (fabsf(E_d - curr) - 0.01f)));
        float E_nf  = dg * curr + (1.0f - dg) * (E_d - dec_d);
        float E_new = fg * O_new + (1.0f - fg) * E_nf;

        const int q = p ^ 1;
        if (h == 0) {
            Eb[q][d] = inj ? ob_next : E_new;
            Ob[q][d] = inj ? ob_next : O_new;
            if (wr) outp[t * NOUT] = E_new;
        }
        __syncthreads();
        p = q;
    }
}

extern "C" void kernel_launch(void* const* d_in, const int* in_sizes, int n_in,
                              void* d_out, int out_size, void* d_ws, size_t ws_size,
                              hipStream_t stream)
{
    const float* obs  = (const float*)d_in[0];
    const float* W    = (const float*)d_in[1];
    const float* thr  = (const float*)d_in[2];
    const float* dec  = (const float*)d_in[3];
    const float* mex  = (const float*)d_in[4];
    const float* min_ = (const float*)d_in[5];
    const float* mgj  = (const float*)d_in[6];
    float* out = (float*)d_out;

    char* ws = (char*)d_ws;
    int*   key_arr = (int*)(ws);
    int*   ccA     = (int*)(ws + 2048);
    int*   cgA     = (int*)(ws + 4096);
    int*   order   = (int*)(ws + 6144);
    int2*  tmpC    = (int2*)(ws + 8192);                   // 512*84*8 = 344064
    int2*  tmpG    = (int2*)(ws + 8192 + 344064);          // 512*52*8 = 212992
    float2* wCt    = (float2*)(ws + 565248);               // 16*21*64*8 = 172032
    unsigned* cpCt = (unsigned*)(ws + 737280);             // 16*21*64*4 =  86016
    float2* wGt    = (float2*)(ws + 823296);               // 16*13*64*8 = 106496
    unsigned* cpGt = (unsigned*)(ws + 929792);             // 16*13*64*4 =  53248
    // total ws use: ~983 KB

    prep1_kernel<<<N_NEUR, 64, 0, stream>>>(W, mex, min_, mgj,
                                            key_arr, ccA, cgA, tmpC, tmpG);
    prep2_kernel<<<N_NEUR, 64, 0, stream>>>(key_arr, ccA, cgA, tmpC, tmpG,
                                            order, wCt, cpCt, wGt, cpGt);
    recur_kernel<<<B_SZ, 1024, 0, stream>>>(obs, thr, dec,
                                            order, ccA, cgA,
                                            wCt, cpCt, wGt, cpGt, out);
}